// Round 3
// baseline (4610.843 us; speedup 1.0000x reference)
//
#include <hip/hip_runtime.h>
#include <cstdint>
#include <cstddef>

// Sinkhorn OT loss, B=4096, D=512.
// K stored bf16 (32MB) only (no KT). Cost matmul via bf16 MFMA hi/lo split.
// Per-iteration single kernel: u-update (row dots) + column-partial
// accumulation of K^T u via atomicAdd (triple-buffered vden). Loss fused
// into last iteration (tden), finished by a tiny 1-block kernel.
// ws layout (bytes):
//   Km  [0, 32MB)            bf16 K
//   Xe  [32MB, +12.6MB)      expanded X (hi|lo|hi) bf16 [4096][1536]
//   Ye  (+12.6MB)            expanded Y (hi|hi|lo)
//   floats after: Xs[4096] Ys[4096] vden[3][4096] tden[4096]

#define N_B 4096
#define N_D 512
#define KE  1536
#define REG_ 0.05f
#define EPS_ 1e-9f
#define INV_N (1.0f / 4096.0f)

typedef __attribute__((ext_vector_type(8))) short bs8;
typedef __attribute__((ext_vector_type(8))) unsigned short us8;
typedef __attribute__((ext_vector_type(4))) float f32x4;

__device__ __forceinline__ float bf2f(unsigned short u) {
  union { uint32_t i; float f; } x; x.i = ((uint32_t)u) << 16; return x.f;
}
__device__ __forceinline__ unsigned short f2bf(float f) {
  union { float f; uint32_t i; } x; x.f = f;
  uint32_t r = (x.i + 0x7FFFu + ((x.i >> 16) & 1u)) >> 16;
  return (unsigned short)r;
}

__device__ __forceinline__ float wave_reduce_sum(float x) {
#pragma unroll
  for (int off = 32; off > 0; off >>= 1) x += __shfl_down(x, off);
  return x;
}

// Expanded operands: Xe=[hi|lo|hi], Ye=[hi|hi|lo] -> K-sum gives
// hi*hi + lo*hi + hi*lo (lo*lo negligible). 8 elements/thread, us8 stores.
__global__ __launch_bounds__(256) void prep_kernel(const float* __restrict__ X,
                                                   const float* __restrict__ Y,
                                                   unsigned short* __restrict__ Xe,
                                                   unsigned short* __restrict__ Ye) {
  int idx = (blockIdx.x * 256 + threadIdx.x) * 8;  // element base
  int row = idx >> 9, col = idx & 511;
  size_t base = (size_t)row * KE + col;
  float fx[8], fy[8];
  *(float4*)&fx[0] = *(const float4*)&X[idx];
  *(float4*)&fx[4] = *(const float4*)&X[idx + 4];
  *(float4*)&fy[0] = *(const float4*)&Y[idx];
  *(float4*)&fy[4] = *(const float4*)&Y[idx + 4];
  us8 xh, xl, yh, yl;
#pragma unroll
  for (int k = 0; k < 8; ++k) {
    unsigned short h = f2bf(fx[k]);
    xh[k] = h; xl[k] = f2bf(fx[k] - bf2f(h));
    unsigned short g = f2bf(fy[k]);
    yh[k] = g; yl[k] = f2bf(fy[k] - bf2f(g));
  }
  *(us8*)&Xe[base] = xh; *(us8*)&Xe[base + 512] = xl; *(us8*)&Xe[base + 1024] = xh;
  *(us8*)&Ye[base] = yh; *(us8*)&Ye[base + 512] = yh; *(us8*)&Ye[base + 1024] = yl;
}

__global__ __launch_bounds__(256) void rownorm_kernel(const float* __restrict__ X,
                                                      float* __restrict__ out) {
  int row = blockIdx.x * 4 + (threadIdx.x >> 6);
  int lane = threadIdx.x & 63;
  const float4* Xr = (const float4*)(X + (size_t)row * N_D);
  float acc = 0.f;
#pragma unroll
  for (int k = lane; k < N_D / 4; k += 64) {
    float4 a = Xr[k];
    acc += a.x * a.x + a.y * a.y + a.z * a.z + a.w * a.w;
  }
  acc = wave_reduce_sum(acc);
  if (lane == 0) out[row] = acc;
}

// vden0 = b - eps  (so first iteration's v = b/(vden0+eps) = 1 exactly-ish),
// vden1 = 0 (iter 0 accumulates into it), tden = 0.
__global__ __launch_bounds__(256) void init_kernel(float* __restrict__ vden0,
                                                   float* __restrict__ vden1,
                                                   float* __restrict__ tden) {
  int i = blockIdx.x * 256 + threadIdx.x;
  vden0[i] = INV_N - EPS_;
  vden1[i] = 0.f;
  tden[i] = 0.f;
}

// 128x128-tile MFMA GEMM: C = Xe . Ye^T over KE=1536,
// epilogue: cost = max(0, Xs+Ys-2C), K = exp(-min(cost,1000)/REG) -> bf16.
__global__ __launch_bounds__(256) void gemm_costK(const unsigned short* __restrict__ Xe,
                                                  const unsigned short* __restrict__ Ye,
                                                  const float* __restrict__ Xs,
                                                  const float* __restrict__ Ys,
                                                  unsigned short* __restrict__ Km) {
  __shared__ unsigned short As[128 * 32];
  __shared__ unsigned short Bs[128 * 32];
  const int tid = threadIdx.x;
  const int lane = tid & 63, w = tid >> 6;
  const int wr = w >> 1, wc = w & 1;
  const int row0 = blockIdx.y * 128, col0 = blockIdx.x * 128;

  f32x4 acc[4][4];
#pragma unroll
  for (int i = 0; i < 4; ++i)
#pragma unroll
    for (int j = 0; j < 4; ++j) acc[i][j] = (f32x4)(0.0f);

  const int srow = tid >> 2;
  const int scol = (tid & 3) * 8;

  for (int k0 = 0; k0 < KE; k0 += 32) {
#pragma unroll
    for (int c = 0; c < 2; ++c) {
      int r = srow + c * 64;
      const unsigned short* ga = Xe + (size_t)(row0 + r) * KE + k0 + scol;
      const unsigned short* gb = Ye + (size_t)(col0 + r) * KE + k0 + scol;
      char* la = (char*)As + c * 4096 + w * 1024;
      char* lb = (char*)Bs + c * 4096 + w * 1024;
      __builtin_amdgcn_global_load_lds((const __attribute__((address_space(1))) void*)ga,
                                       (__attribute__((address_space(3))) void*)la, 16, 0, 0);
      __builtin_amdgcn_global_load_lds((const __attribute__((address_space(1))) void*)gb,
                                       (__attribute__((address_space(3))) void*)lb, 16, 0, 0);
    }
    __syncthreads();
    bs8 af[4], bfr[4];
#pragma unroll
    for (int f = 0; f < 4; ++f) {
      af[f]  = *(const bs8*)&As[(wr * 64 + f * 16 + (lane & 15)) * 32 + (lane >> 4) * 8];
      bfr[f] = *(const bs8*)&Bs[(wc * 64 + f * 16 + (lane & 15)) * 32 + (lane >> 4) * 8];
    }
#pragma unroll
    for (int i = 0; i < 4; ++i)
#pragma unroll
      for (int j = 0; j < 4; ++j)
        acc[i][j] = __builtin_amdgcn_mfma_f32_16x16x32_bf16(af[i], bfr[j], acc[i][j], 0, 0, 0);
    __syncthreads();
  }

#pragma unroll
  for (int j = 0; j < 4; ++j) {
    int col = col0 + wc * 64 + j * 16 + (lane & 15);
    float ys = Ys[col];
#pragma unroll
    for (int i = 0; i < 4; ++i) {
#pragma unroll
      for (int q = 0; q < 4; ++q) {
        int row = row0 + wr * 64 + i * 16 + (lane >> 4) * 4 + q;
        float cost = fmaxf(Xs[row] + ys - 2.0f * acc[i][j][q], 0.0f);
        float kf = expf(-fminf(cost, 1000.0f) * (1.0f / REG_));
        Km[(size_t)row * N_B + col] = f2bf(kf);
      }
    }
  }
}

// One Sinkhorn iteration. Block owns 16 rows of K (256 blocks, 8 waves).
// Step0: v = b/(vdenR+eps) into LDS; zero vdenZ (for iteration t+1's adds).
// Phase1: u_i = a/(dot(K_i, v)+eps) for the block's rows.
// Phase2: per-wave column stripe (512 cols), accumulate sum_i K_ij*u_i and
// atomicAdd into vdenA. If LAST, also accumulate t_j = sum_i u_i K_ij c_ij.
template <bool LAST>
__global__ __launch_bounds__(512) void iter_kernel(const unsigned short* __restrict__ Km,
                                                   const float* __restrict__ vdenR,
                                                   float* __restrict__ vdenA,
                                                   float* __restrict__ vdenZ,
                                                   float* __restrict__ tden) {
  __shared__ float v_sh[N_B];
  __shared__ float u_sh[16];
  const int tid = threadIdx.x;
  const int bid = blockIdx.x;
  const int row0 = bid * 16;

  for (int i = tid; i < N_B; i += 512) v_sh[i] = INV_N / (vdenR[i] + EPS_);
  if (tid < 16) vdenZ[row0 + tid] = 0.0f;
  __syncthreads();

  const int wv = tid >> 6, lane = tid & 63;
  // phase 1: wave wv handles rows 2wv and 2wv+1
#pragma unroll
  for (int rr = 0; rr < 2; ++rr) {
    int r = wv * 2 + rr;
    const us8* Mr = (const us8*)(Km + (size_t)(row0 + r) * N_B);
    float a0 = 0.f, a1 = 0.f;
#pragma unroll
    for (int it = 0; it < 8; ++it) {
      int c = it * 64 + lane;
      us8 m = Mr[c];
      const float* vv = &v_sh[c * 8];
      a0 += bf2f(m[0]) * vv[0] + bf2f(m[2]) * vv[2] + bf2f(m[4]) * vv[4] + bf2f(m[6]) * vv[6];
      a1 += bf2f(m[1]) * vv[1] + bf2f(m[3]) * vv[3] + bf2f(m[5]) * vv[5] + bf2f(m[7]) * vv[7];
    }
    float acc = wave_reduce_sum(a0 + a1);
    if (lane == 0) u_sh[r] = INV_N / (acc + EPS_);
  }
  __syncthreads();

  // phase 2: wave wv owns cols [wv*512, wv*512+512); lane owns 8 of them.
  const int col0 = wv * 512 + lane * 8;
  float vacc[8] = {0, 0, 0, 0, 0, 0, 0, 0};
  float tacc[8] = {0, 0, 0, 0, 0, 0, 0, 0};
#pragma unroll
  for (int r = 0; r < 16; ++r) {
    float ur = u_sh[r];
    us8 m = *(const us8*)&Km[(size_t)(row0 + r) * N_B + col0];
#pragma unroll
    for (int k = 0; k < 8; ++k) {
      float kf = bf2f(m[k]);
      vacc[k] += kf * ur;
      if (LAST) {
        float c = -REG_ * logf(fmaxf(kf, 1e-30f));  // guard 0*inf
        tacc[k] += (ur * kf) * c;
      }
    }
  }
#pragma unroll
  for (int k = 0; k < 8; ++k) atomicAdd(&vdenA[col0 + k], vacc[k]);
  if (LAST) {
#pragma unroll
    for (int k = 0; k < 8; ++k) atomicAdd(&tden[col0 + k], tacc[k]);
  }
}

// loss = sum_j (b/(vden_final_j+eps)) * t_j  -- single block.
__global__ __launch_bounds__(256) void loss_final(const float* __restrict__ vden,
                                                  const float* __restrict__ tden,
                                                  float* __restrict__ out) {
  __shared__ float wp[4];
  const int tid = threadIdx.x;
  float acc = 0.f;
  for (int j = tid; j < N_B; j += 256)
    acc += (INV_N / (vden[j] + EPS_)) * tden[j];
  acc = wave_reduce_sum(acc);
  int wid = tid >> 6, lane = tid & 63;
  if (lane == 0) wp[wid] = acc;
  __syncthreads();
  if (tid == 0) out[0] = wp[0] + wp[1] + wp[2] + wp[3];
}

extern "C" void kernel_launch(void* const* d_in, const int* in_sizes, int n_in,
                              void* d_out, int out_size, void* d_ws, size_t ws_size,
                              hipStream_t stream) {
  const float* X = (const float*)d_in[0];
  const float* Y = (const float*)d_in[1];
  float* out = (float*)d_out;
  char* w = (char*)d_ws;

  const size_t MB = 1024 * 1024;
  unsigned short* Km = (unsigned short*)w;
  unsigned short* Xe = (unsigned short*)(w + 32 * MB);
  unsigned short* Ye = (unsigned short*)(w + 32 * MB + (size_t)N_B * KE * 2);
  float* Xs = (float*)(w + 32 * MB + (size_t)2 * N_B * KE * 2);
  float* Ys = Xs + N_B;
  float* vden0 = Ys + N_B;
  float* vden1 = vden0 + N_B;
  float* vden2 = vden1 + N_B;
  float* tden = vden2 + N_B;
  float* vden[3] = {vden0, vden1, vden2};

  prep_kernel<<<N_B * N_D / (256 * 8), 256, 0, stream>>>(X, Y, Xe, Ye);
  rownorm_kernel<<<N_B / 4, 256, 0, stream>>>(X, Xs);
  rownorm_kernel<<<N_B / 4, 256, 0, stream>>>(Y, Ys);
  init_kernel<<<N_B / 256, 256, 0, stream>>>(vden0, vden1, tden);

  gemm_costK<<<dim3(32, 32), 256, 0, stream>>>(Xe, Ye, Xs, Ys, Km);

  for (int t = 0; t < 50; ++t) {
    float* R = vden[t % 3];
    float* A = vden[(t + 1) % 3];
    float* Z = vden[(t + 2) % 3];
    if (t < 49)
      iter_kernel<false><<<256, 512, 0, stream>>>(Km, R, A, Z, tden);
    else
      iter_kernel<true><<<256, 512, 0, stream>>>(Km, R, A, Z, tden);
  }

  // final v lives in vden[(49+1)%3] = vden[2]
  loss_final<<<1, 256, 0, stream>>>(vden[50 % 3], tden, out);
}

// Round 5
// 797.375 us; speedup vs baseline: 5.7825x; 5.7825x over previous
//
#include <hip/hip_runtime.h>
#include <hip/hip_fp16.h>
#include <cstdint>
#include <cstddef>

// Sinkhorn OT loss, B=4096, D=512.
// Round 4 (resubmit): round-2 structure (separate matvec kernels; NO atomics)
// but K and KT stored as SCALED fp8-e5m2: Ks = K * 2^28. Sinkhorn recurrence
// is scale-invariant (eps negligible), gamma = u*Ks*v is unchanged, and
// cost = REG*(28*ln2 - ln Ks) in the loss pass.
// ws layout (bytes):
//   Km  [0, 16MB)       fp8 Ks
//   KTm [16MB, 32MB)    fp8 Ks^T
//   Xe  [32MB, +12.6MB) expanded X (hi|lo|hi) bf16 [4096][1536]
//   Ye  (+12.6MB)       expanded Y (hi|hi|lo)
//   floats after: Xs[4096] Ys[4096] u[4096] v[4096]

#define N_B 4096
#define N_D 512
#define KE  1536
#define REG_ 0.05f
#define EPS_ 1e-9f
#define INV_N (1.0f / 4096.0f)
#define SCALE_LOG 28.0f          // Ks = K * 2^28
#define LN2_ 0.69314718f

typedef __attribute__((ext_vector_type(8))) short bs8;
typedef __attribute__((ext_vector_type(8))) unsigned short us8;
typedef __attribute__((ext_vector_type(4))) float f32x4;

__device__ __forceinline__ float bf2f(unsigned short u) {
  union { uint32_t i; float f; } x; x.i = ((uint32_t)u) << 16; return x.f;
}
__device__ __forceinline__ unsigned short f2bf(float f) {
  union { float f; uint32_t i; } x; x.f = f;
  uint32_t r = (x.i + 0x7FFFu + ((x.i >> 16) & 1u)) >> 16;
  return (unsigned short)r;
}
// e5m2 = top byte of fp16 (RNE). Clamp first so rounding can't hit inf.
__device__ __forceinline__ unsigned char f2fp8(float f) {
  f = fminf(f, 57344.0f);
  __half h = __float2half(f);
  unsigned short hb = *(unsigned short*)&h;
  unsigned short r = (unsigned short)((hb + 0x7F + ((hb >> 8) & 1)) >> 8);
  return (unsigned char)r;
}
__device__ __forceinline__ float fp82f(uint32_t b) {
  unsigned short hb = (unsigned short)(b << 8);
  __half h = *(__half*)&hb;
  return __half2float(h);
}

__device__ __forceinline__ float wave_reduce_sum(float x) {
#pragma unroll
  for (int off = 32; off > 0; off >>= 1) x += __shfl_down(x, off);
  return x;
}

// Expanded operands: Xe=[hi|lo|hi], Ye=[hi|hi|lo] -> K-sum gives
// hi*hi + lo*hi + hi*lo (lo*lo negligible).
__global__ __launch_bounds__(256) void prep_kernel(const float* __restrict__ X,
                                                   const float* __restrict__ Y,
                                                   unsigned short* __restrict__ Xe,
                                                   unsigned short* __restrict__ Ye) {
  int idx = (blockIdx.x * 256 + threadIdx.x) * 8;
  int row = idx >> 9, col = idx & 511;
  size_t base = (size_t)row * KE + col;
  float fx[8], fy[8];
  *(float4*)&fx[0] = *(const float4*)&X[idx];
  *(float4*)&fx[4] = *(const float4*)&X[idx + 4];
  *(float4*)&fy[0] = *(const float4*)&Y[idx];
  *(float4*)&fy[4] = *(const float4*)&Y[idx + 4];
  us8 xh, xl, yh, yl;
#pragma unroll
  for (int k = 0; k < 8; ++k) {
    unsigned short h = f2bf(fx[k]);
    xh[k] = h; xl[k] = f2bf(fx[k] - bf2f(h));
    unsigned short g = f2bf(fy[k]);
    yh[k] = g; yl[k] = f2bf(fy[k] - bf2f(g));
  }
  *(us8*)&Xe[base] = xh; *(us8*)&Xe[base + 512] = xl; *(us8*)&Xe[base + 1024] = xh;
  *(us8*)&Ye[base] = yh; *(us8*)&Ye[base + 512] = yh; *(us8*)&Ye[base + 1024] = yl;
}

__global__ __launch_bounds__(256) void rownorm_kernel(const float* __restrict__ X,
                                                      float* __restrict__ out) {
  int row = blockIdx.x * 4 + (threadIdx.x >> 6);
  int lane = threadIdx.x & 63;
  const float4* Xr = (const float4*)(X + (size_t)row * N_D);
  float acc = 0.f;
#pragma unroll
  for (int k = lane; k < N_D / 4; k += 64) {
    float4 a = Xr[k];
    acc += a.x * a.x + a.y * a.y + a.z * a.z + a.w * a.w;
  }
  acc = wave_reduce_sum(acc);
  if (lane == 0) out[row] = acc;
}

__global__ __launch_bounds__(256) void init_v_kernel(float* __restrict__ v) {
  int i = blockIdx.x * 256 + threadIdx.x;
  if (i < N_B) v[i] = 1.0f;
}

// 128x128-tile MFMA GEMM: C = Xe . Ye^T over KE=1536,
// epilogue: cost=max(0,Xs+Ys-2C); Ks=exp(28*ln2 - cost/REG) -> fp8 e5m2.
__global__ __launch_bounds__(256) void gemm_costK(const unsigned short* __restrict__ Xe,
                                                  const unsigned short* __restrict__ Ye,
                                                  const float* __restrict__ Xs,
                                                  const float* __restrict__ Ys,
                                                  unsigned char* __restrict__ Km) {
  __shared__ unsigned short As[128 * 32];
  __shared__ unsigned short Bs[128 * 32];
  const int tid = threadIdx.x;
  const int lane = tid & 63, w = tid >> 6;
  const int wr = w >> 1, wc = w & 1;
  const int row0 = blockIdx.y * 128, col0 = blockIdx.x * 128;

  f32x4 acc[4][4];
#pragma unroll
  for (int i = 0; i < 4; ++i)
#pragma unroll
    for (int j = 0; j < 4; ++j) acc[i][j] = (f32x4)(0.0f);

  const int srow = tid >> 2;
  const int scol = (tid & 3) * 8;

  for (int k0 = 0; k0 < KE; k0 += 32) {
#pragma unroll
    for (int c = 0; c < 2; ++c) {
      int r = srow + c * 64;
      const unsigned short* ga = Xe + (size_t)(row0 + r) * KE + k0 + scol;
      const unsigned short* gb = Ye + (size_t)(col0 + r) * KE + k0 + scol;
      char* la = (char*)As + c * 4096 + w * 1024;
      char* lb = (char*)Bs + c * 4096 + w * 1024;
      __builtin_amdgcn_global_load_lds((const __attribute__((address_space(1))) void*)ga,
                                       (__attribute__((address_space(3))) void*)la, 16, 0, 0);
      __builtin_amdgcn_global_load_lds((const __attribute__((address_space(1))) void*)gb,
                                       (__attribute__((address_space(3))) void*)lb, 16, 0, 0);
    }
    __syncthreads();
    bs8 af[4], bfr[4];
#pragma unroll
    for (int f = 0; f < 4; ++f) {
      af[f]  = *(const bs8*)&As[(wr * 64 + f * 16 + (lane & 15)) * 32 + (lane >> 4) * 8];
      bfr[f] = *(const bs8*)&Bs[(wc * 64 + f * 16 + (lane & 15)) * 32 + (lane >> 4) * 8];
    }
#pragma unroll
    for (int i = 0; i < 4; ++i)
#pragma unroll
      for (int j = 0; j < 4; ++j)
        acc[i][j] = __builtin_amdgcn_mfma_f32_16x16x32_bf16(af[i], bfr[j], acc[i][j], 0, 0, 0);
    __syncthreads();
  }

#pragma unroll
  for (int j = 0; j < 4; ++j) {
    int col = col0 + wc * 64 + j * 16 + (lane & 15);
    float ys = Ys[col];
#pragma unroll
    for (int i = 0; i < 4; ++i) {
#pragma unroll
      for (int q = 0; q < 4; ++q) {
        int row = row0 + wr * 64 + i * 16 + (lane >> 4) * 4 + q;
        float cost = fmaxf(Xs[row] + ys - 2.0f * acc[i][j][q], 0.0f);
        float ks = expf(SCALE_LOG * LN2_ - fminf(cost, 1000.0f) * (1.0f / REG_));
        Km[(size_t)row * N_B + col] = f2fp8(ks);
      }
    }
  }
}

// 64x64 byte-tile transpose for fp8 K.
__global__ __launch_bounds__(256) void transpose_fp8(const unsigned char* __restrict__ in,
                                                     unsigned char* __restrict__ out) {
  __shared__ unsigned char t[64][68];
  const int tid = threadIdx.x;
  const int r0 = blockIdx.y * 64, c0 = blockIdx.x * 64;
  {
    int r = tid >> 2, off = (tid & 3) * 16;
    uint4 m = *(const uint4*)&in[(size_t)(r0 + r) * N_B + c0 + off];
    *(uint4*)&t[r][off] = m;  // t row is 68B-padded; off multiple of 16 -> 16B aligned
  }
  __syncthreads();
  {
    int j = tid >> 2, off = (tid & 3) * 16;
    unsigned char b[16];
#pragma unroll
    for (int k = 0; k < 16; ++k) b[k] = t[off + k][j];
    *(uint4*)&out[(size_t)(c0 + j) * N_B + r0 + off] = *(uint4*)b;
  }
}

// One wave per row: out[row] = scale / (dot(M_fp8[row][:], x) + EPS)
__global__ __launch_bounds__(256) void matvec_fp8(const unsigned char* __restrict__ M,
                                                  const float* __restrict__ x,
                                                  float* __restrict__ out, float scale) {
  int row = blockIdx.x * 4 + (threadIdx.x >> 6);
  int lane = threadIdx.x & 63;
  const uint4* Mr = (const uint4*)(M + (size_t)row * N_B);  // 16 fp8 / uint4
  const float4* xv = (const float4*)x;
  float acc = 0.f;
#pragma unroll
  for (int it = 0; it < 4; ++it) {
    int c = it * 64 + lane;
    uint4 m = Mr[c];
    float4 x0 = xv[c * 4], x1 = xv[c * 4 + 1], x2 = xv[c * 4 + 2], x3 = xv[c * 4 + 3];
    acc += fp82f(m.x & 0xFF) * x0.x + fp82f((m.x >> 8) & 0xFF) * x0.y +
           fp82f((m.x >> 16) & 0xFF) * x0.z + fp82f(m.x >> 24) * x0.w;
    acc += fp82f(m.y & 0xFF) * x1.x + fp82f((m.y >> 8) & 0xFF) * x1.y +
           fp82f((m.y >> 16) & 0xFF) * x1.z + fp82f(m.y >> 24) * x1.w;
    acc += fp82f(m.z & 0xFF) * x2.x + fp82f((m.z >> 8) & 0xFF) * x2.y +
           fp82f((m.z >> 16) & 0xFF) * x2.z + fp82f(m.z >> 24) * x2.w;
    acc += fp82f(m.w & 0xFF) * x3.x + fp82f((m.w >> 8) & 0xFF) * x3.y +
           fp82f((m.w >> 16) & 0xFF) * x3.z + fp82f(m.w >> 24) * x3.w;
  }
  acc = wave_reduce_sum(acc);
  if (lane == 0) out[row] = scale / (acc + EPS_);
}

// loss = sum_ij u_i Ks_ij v_j * cost_ij, cost = REG*(28*ln2 - ln Ks).
__global__ __launch_bounds__(256) void loss_kernel(const unsigned char* __restrict__ Km,
                                                   const float* __restrict__ u,
                                                   const float* __restrict__ v,
                                                   float* __restrict__ out) {
  const size_t NC = (size_t)N_B * N_B / 16;
  float acc = 0.f;
  for (size_t c = (size_t)blockIdx.x * 256 + threadIdx.x; c < NC; c += (size_t)gridDim.x * 256) {
    size_t e = c * 16;
    int i = (int)(e >> 12);
    int j = (int)(e & (N_B - 1));
    uint4 m = *(const uint4*)&Km[e];
    float ui = u[i];
    uint32_t parts[4] = {m.x, m.y, m.z, m.w};
#pragma unroll
    for (int p = 0; p < 4; ++p) {
#pragma unroll
      for (int b = 0; b < 4; ++b) {
        float kf = fp82f((parts[p] >> (8 * b)) & 0xFF);
        float cst = REG_ * (SCALE_LOG * LN2_ - logf(fmaxf(kf, 1e-30f)));
        acc += (ui * kf) * (v[j + p * 4 + b] * cst);
      }
    }
  }
  acc = wave_reduce_sum(acc);
  __shared__ float wp[4];
  int wid = threadIdx.x >> 6, lane = threadIdx.x & 63;
  if (lane == 0) wp[wid] = acc;
  __syncthreads();
  if (threadIdx.x == 0) atomicAdd(out, wp[0] + wp[1] + wp[2] + wp[3]);
}

extern "C" void kernel_launch(void* const* d_in, const int* in_sizes, int n_in,
                              void* d_out, int out_size, void* d_ws, size_t ws_size,
                              hipStream_t stream) {
  const float* X = (const float*)d_in[0];
  const float* Y = (const float*)d_in[1];
  float* out = (float*)d_out;
  char* w = (char*)d_ws;

  const size_t MB = 1024 * 1024;
  unsigned char* Km  = (unsigned char*)w;
  unsigned char* KTm = (unsigned char*)(w + 16 * MB);
  unsigned short* Xe = (unsigned short*)(w + 32 * MB);
  unsigned short* Ye = (unsigned short*)(w + 32 * MB + (size_t)N_B * KE * 2);
  float* Xs = (float*)(w + 32 * MB + (size_t)2 * N_B * KE * 2);
  float* Ys = Xs + N_B;
  float* u  = Ys + N_B;
  float* v  = u + N_B;

  hipMemsetAsync(d_out, 0, sizeof(float), stream);

  prep_kernel<<<N_B * N_D / (256 * 8), 256, 0, stream>>>(X, Y, Xe, Ye);
  rownorm_kernel<<<N_B / 4, 256, 0, stream>>>(X, Xs);
  rownorm_kernel<<<N_B / 4, 256, 0, stream>>>(Y, Ys);
  init_v_kernel<<<N_B / 256, 256, 0, stream>>>(v);

  gemm_costK<<<dim3(32, 32), 256, 0, stream>>>(Xe, Ye, Xs, Ys, Km);
  transpose_fp8<<<dim3(64, 64), 256, 0, stream>>>(Km, KTm);

  for (int it = 0; it < 50; ++it) {
    matvec_fp8<<<N_B / 4, 256, 0, stream>>>(Km, v, u, INV_N);
    matvec_fp8<<<N_B / 4, 256, 0, stream>>>(KTm, u, v, INV_N);
  }

  loss_kernel<<<2048, 256, 0, stream>>>(Km, u, v, out);
}